// Round 11
// baseline (1947.966 us; speedup 1.0000x reference)
//
#include <hip/hip_runtime.h>
#include <cstdint>

#define NB 16384   // batch
#define NM 256     // M
#define NN 1024    // N
#define NITER 16
#define TOPK 50

typedef __attribute__((ext_vector_type(8))) short short8;   // 8 bf16 = 4 VGPRs
typedef __attribute__((ext_vector_type(4))) float f32x4;

__device__ inline unsigned short f2bf(float x) {            // RNE fp32 -> bf16
    unsigned u = __float_as_uint(x);
    return (unsigned short)((u + 0x7FFFu + ((u >> 16) & 1u)) >> 16);
}
__device__ inline float bf2f(unsigned short h) {
    return __uint_as_float(((unsigned)h) << 16);
}
__device__ inline void gload16(const void* g, void* lds) {  // 16B global -> LDS
    __builtin_amdgcn_global_load_lds(
        (const __attribute__((address_space(1))) unsigned*)g,
        (__attribute__((address_space(3))) unsigned*)lds, 16, 0, 0);
}

// ------------- precompute: element-wise split of phi (NM x NN) -------------
__global__ __launch_bounds__(256) void split_phi_kernel(const float* __restrict__ phi,
                                                        unsigned short* __restrict__ h,
                                                        unsigned short* __restrict__ l) {
    int i = blockIdx.x * 256 + threadIdx.x;
    float v = phi[i];
    unsigned short hh = f2bf(v);
    h[i] = hh;
    l[i] = f2bf(v - bf2f(hh));
}

// -------- precompute: W (NM x NN) -> Wt (NN x NM) transposed + split -------
__global__ __launch_bounds__(256) void transpose_split_W(const float* __restrict__ W,
                                                         unsigned short* __restrict__ th,
                                                         unsigned short* __restrict__ tl) {
    __shared__ float tile[32][33];
    int n0 = blockIdx.x * 32;
    int m0 = blockIdx.y * 32;
    int tx = threadIdx.x;   // 0..31
    int ty = threadIdx.y;   // 0..7
    #pragma unroll
    for (int i = 0; i < 32; i += 8)
        tile[ty + i][tx] = W[(size_t)(m0 + ty + i) * NN + n0 + tx];
    __syncthreads();
    #pragma unroll
    for (int i = 0; i < 32; i += 8) {
        float v = tile[tx][ty + i];
        unsigned short hh = f2bf(v);
        size_t idx = (size_t)(n0 + ty + i) * NM + m0 + tx;
        th[idx] = hh;
        tl[idx] = f2bf(v - bf2f(hh));
    }
}

// ---- it=0 shortcut: X==0 -> Rt = -y (split). Replaces memsets + gemm1. ----
__global__ __launch_bounds__(256) void rt_init_kernel(const float* __restrict__ y,
                                                      unsigned short* __restrict__ Rth,
                                                      unsigned short* __restrict__ Rtl) {
    size_t i = ((size_t)blockIdx.x * 256 + threadIdx.x) * 4;
    float4 v4 = *reinterpret_cast<const float4*>(&y[i]);
    float vv[4] = {v4.x, v4.y, v4.z, v4.w};
    ushort4 h4, l4;
    unsigned short* hp = reinterpret_cast<unsigned short*>(&h4);
    unsigned short* lp = reinterpret_cast<unsigned short*>(&l4);
    #pragma unroll
    for (int e = 0; e < 4; ++e) {
        float v = -vv[e];
        unsigned short h = f2bf(v);
        hp[e] = h;
        lp[e] = f2bf(v - bf2f(h));
    }
    *reinterpret_cast<ushort4*>(&Rth[i]) = h4;
    *reinterpret_cast<ushort4*>(&Rtl[i]) = l4;
}

// ---- GEMM1: Rt(B x NM) = X(B x NN) @ phiT - y ----
// 64x64 tile (was 128x64): grid 512 -> 1024 blocks, LDS 24 -> 16 KB.
// Round-10 counters: 2 blocks/CU x 4 waves = 8 waves/CU (Occupancy ~20%),
// latency-bound at barriers. 4 blocks/CU doubles resident waves; MFMA
// order per k-step unchanged (ah*bh, ah*bl, al*bh) -> bit-identical Rt.
#define BM1 64
#define BN1 64
#define BK  32
__global__ __launch_bounds__(256) void gemm1_mfma(const unsigned short* __restrict__ Xh,
                                                  const unsigned short* __restrict__ Xl,
                                                  const unsigned short* __restrict__ Ph,
                                                  const unsigned short* __restrict__ Pl,
                                                  const float* __restrict__ y,
                                                  unsigned short* __restrict__ Rth,
                                                  unsigned short* __restrict__ Rtl) {
    __shared__ unsigned short sAh[BM1 * BK];  // 4KB each, row = 32 elem = 64B
    __shared__ unsigned short sAl[BM1 * BK];
    __shared__ unsigned short sBh[BN1 * BK];
    __shared__ unsigned short sBl[BN1 * BK];

    const int tid = threadIdx.x, wave = tid >> 6, lane = tid & 63;
    const int b0 = blockIdx.x * BM1, n0 = blockIdx.y * BN1;
    const int wm = (wave & 1) * 32, wn = (wave >> 1) * 32;
    const int row16 = lane & 15, quad = lane >> 4;

    f32x4 acc[2][2];
    #pragma unroll
    for (int i = 0; i < 2; i++)
        #pragma unroll
        for (int j = 0; j < 2; j++) acc[i][j] = (f32x4){0.f, 0.f, 0.f, 0.f};

    for (int k0 = 0; k0 < NN; k0 += BK) {
        {   // stage A+B: one 16B chunk per thread per array (4KB tiles)
            int o = tid * 16;                  // byte offset in tile
            int row = o >> 6, colb = o & 63;
            size_t gA = (size_t)(b0 + row) * NN + k0 + (colb >> 1);
            gload16(&Xh[gA], (char*)sAh + o);
            gload16(&Xl[gA], (char*)sAl + o);
            size_t gB = (size_t)(n0 + row) * NN + k0 + (colb >> 1);
            gload16(&Ph[gB], (char*)sBh + o);
            gload16(&Pl[gB], (char*)sBl + o);
        }
        __syncthreads();
        short8 a[2], bh[2], bl[2];
        #pragma unroll
        for (int j = 0; j < 2; ++j) {
            int off = (wn + j * 16 + row16) * 64 + quad * 16;
            bh[j] = *(const short8*)((const char*)sBh + off);
            bl[j] = *(const short8*)((const char*)sBl + off);
        }
        #pragma unroll
        for (int i = 0; i < 2; ++i)
            a[i] = *(const short8*)((const char*)sAh + (wm + i * 16 + row16) * 64 + quad * 16);
        #pragma unroll
        for (int i = 0; i < 2; ++i)
            #pragma unroll
            for (int j = 0; j < 2; ++j) {
                acc[i][j] = __builtin_amdgcn_mfma_f32_16x16x32_bf16(a[i], bh[j], acc[i][j], 0, 0, 0);
                acc[i][j] = __builtin_amdgcn_mfma_f32_16x16x32_bf16(a[i], bl[j], acc[i][j], 0, 0, 0);
            }
        #pragma unroll
        for (int i = 0; i < 2; ++i)
            a[i] = *(const short8*)((const char*)sAl + (wm + i * 16 + row16) * 64 + quad * 16);
        #pragma unroll
        for (int i = 0; i < 2; ++i)
            #pragma unroll
            for (int j = 0; j < 2; ++j)
                acc[i][j] = __builtin_amdgcn_mfma_f32_16x16x32_bf16(a[i], bh[j], acc[i][j], 0, 0, 0);
        __syncthreads();
    }
    #pragma unroll
    for (int i = 0; i < 2; ++i)
        #pragma unroll
        for (int j = 0; j < 2; ++j)
            #pragma unroll
            for (int r = 0; r < 4; ++r) {
                int gm = b0 + wm + i * 16 + quad * 4 + r;
                int gn = n0 + wn + j * 16 + row16;
                size_t idx = (size_t)gm * NM + gn;
                float v = acc[i][j][r] - y[idx];
                unsigned short h = f2bf(v);
                Rth[idx] = h;
                Rtl[idx] = f2bf(v - bf2f(h));
            }
}

// ---- GEMM2 lean: C(B x NN) = Rt(B x NM) @ W(NM x NN), raw f32 out ----
#define BM2 128
#define BN2 128
__global__ __launch_bounds__(256) void gemm2_mfma(const unsigned short* __restrict__ Rth,
                                                  const unsigned short* __restrict__ Rtl,
                                                  const unsigned short* __restrict__ Wth,
                                                  const unsigned short* __restrict__ Wtl,
                                                  float* __restrict__ C) {
    __shared__ unsigned short sAh[BM2 * BK];  // 8KB each
    __shared__ unsigned short sAl[BM2 * BK];
    __shared__ unsigned short sBh[BN2 * BK];
    __shared__ unsigned short sBl[BN2 * BK];

    const int tid = threadIdx.x, wave = tid >> 6, lane = tid & 63;
    const int b0 = blockIdx.x * BM2, n0 = blockIdx.y * BN2;
    const int wm = (wave & 1) * 64, wn = (wave >> 1) * 64;
    const int row16 = lane & 15, quad = lane >> 4;

    f32x4 acc[4][4];
    #pragma unroll
    for (int i = 0; i < 4; i++)
        #pragma unroll
        for (int j = 0; j < 4; j++) acc[i][j] = (f32x4){0.f, 0.f, 0.f, 0.f};

    for (int k0 = 0; k0 < NM; k0 += BK) {
        #pragma unroll
        for (int c = 0; c < 2; ++c) {
            int o = (wave * 2 + c) * 1024 + lane * 16;
            int row = o >> 6, colb = o & 63;
            size_t gA = (size_t)(b0 + row) * NM + k0 + (colb >> 1);
            gload16(&Rth[gA], (char*)sAh + o);
            gload16(&Rtl[gA], (char*)sAl + o);
            size_t gB = (size_t)(n0 + row) * NM + k0 + (colb >> 1);
            gload16(&Wth[gB], (char*)sBh + o);
            gload16(&Wtl[gB], (char*)sBl + o);
        }
        __syncthreads();
        short8 a[4], bh[4], bl[4];
        #pragma unroll
        for (int j = 0; j < 4; ++j) {
            int off = (wn + j * 16 + row16) * 64 + quad * 16;
            bh[j] = *(const short8*)((const char*)sBh + off);
            bl[j] = *(const short8*)((const char*)sBl + off);
        }
        #pragma unroll
        for (int i = 0; i < 4; ++i)
            a[i] = *(const short8*)((const char*)sAh + (wm + i * 16 + row16) * 64 + quad * 16);
        #pragma unroll
        for (int i = 0; i < 4; ++i)
            #pragma unroll
            for (int j = 0; j < 4; ++j) {
                acc[i][j] = __builtin_amdgcn_mfma_f32_16x16x32_bf16(a[i], bh[j], acc[i][j], 0, 0, 0);
                acc[i][j] = __builtin_amdgcn_mfma_f32_16x16x32_bf16(a[i], bl[j], acc[i][j], 0, 0, 0);
            }
        #pragma unroll
        for (int i = 0; i < 4; ++i)
            a[i] = *(const short8*)((const char*)sAl + (wm + i * 16 + row16) * 64 + quad * 16);
        #pragma unroll
        for (int i = 0; i < 4; ++i)
            #pragma unroll
            for (int j = 0; j < 4; ++j)
                acc[i][j] = __builtin_amdgcn_mfma_f32_16x16x32_bf16(a[i], bh[j], acc[i][j], 0, 0, 0);
        __syncthreads();
    }
    #pragma unroll
    for (int i = 0; i < 4; ++i)
        #pragma unroll
        for (int j = 0; j < 4; ++j)
            #pragma unroll
            for (int r = 0; r < 4; ++r) {
                int gmr = b0 + wm + i * 16 + quad * 4 + r;
                int gn = n0 + wn + j * 16 + row16;
                C[(size_t)gmr * NN + gn] = acc[i][j][r];
            }
}

// -------- update: v = x - gamma*c, exact top-50 |v| via 1024-bin select ----
// LAST: final iteration's X write is dead (only `out` is consumed) -> skip.
template <int FIRST, int LAST>
__global__ __launch_bounds__(256) void update_kernel(const float* __restrict__ C,
                                                     unsigned short* __restrict__ Xh,
                                                     unsigned short* __restrict__ Xl,
                                                     const float* __restrict__ gamma,
                                                     const float* __restrict__ theta,
                                                     int it,
                                                     float* __restrict__ out) {
    __shared__ unsigned hist[1024];    // 4KB
    __shared__ unsigned wtot[4];
    __shared__ unsigned s_bin;
    __shared__ unsigned s_r2;
    __shared__ unsigned s_cnt;
    __shared__ unsigned s_T;
    __shared__ unsigned s_low[1024];   // 4KB worst case

    const int b = blockIdx.x, tid = threadIdx.x;
    const int lane = tid & 63, wave = tid >> 6;
    const size_t base = (size_t)b * NN + tid * 4;
    const float gm = gamma[it];

    float4 cc = *reinterpret_cast<const float4*>(&C[base]);
    float c4[4] = {cc.x, cc.y, cc.z, cc.w};

    ushort4 xh4, xl4;
    float xo[4];
    if (FIRST) {
        xo[0] = xo[1] = xo[2] = xo[3] = 0.0f;
    } else {
        xh4 = *reinterpret_cast<const ushort4*>(&Xh[base]);
        xl4 = *reinterpret_cast<const ushort4*>(&Xl[base]);
        const unsigned short* xhp = reinterpret_cast<const unsigned short*>(&xh4);
        const unsigned short* xlp = reinterpret_cast<const unsigned short*>(&xl4);
        #pragma unroll
        for (int j = 0; j < 4; j++) xo[j] = bf2f(xhp[j]) + bf2f(xlp[j]);
    }

    float v[4];
    unsigned u[4];
    #pragma unroll
    for (int j = 0; j < 4; j++) {
        v[j] = xo[j] - gm * c4[j];
        u[j] = __float_as_uint(fabsf(v[j]));
    }

    // clear
    uint4 z4 = {0u, 0u, 0u, 0u};
    reinterpret_cast<uint4*>(hist)[tid] = z4;
    if (tid == 0) s_cnt = 0;
    __syncthreads();

    #pragma unroll
    for (int j = 0; j < 4; j++) atomicAdd(&hist[u[j] >> 21], 1u);
    __syncthreads();

    // thread t owns bins [t*4, t*4+4)
    unsigned loc[4];
    uint4 h0 = reinterpret_cast<const uint4*>(hist)[tid];
    loc[0] = h0.x; loc[1] = h0.y; loc[2] = h0.z; loc[3] = h0.w;
    unsigned lsum = loc[0] + loc[1] + loc[2] + loc[3];

    // wave-level inclusive suffix scan of lsum (no LDS, no barriers)
    unsigned s = lsum;
    #pragma unroll
    for (int off = 1; off < 64; off <<= 1) {
        unsigned o = __shfl_down(s, off, 64);
        if (lane + off < 64) s += o;
    }
    if (lane == 0) wtot[wave] = s;   // wave total
    __syncthreads();
    unsigned after_wave = 0;
    #pragma unroll
    for (int w = 0; w < 4; ++w)
        if (w > wave) after_wave += wtot[w];
    unsigned S_incl = s + after_wave;      // suffix incl. this thread's bins
    unsigned run = S_incl - lsum;          // suffix of all higher bins

    const unsigned r = TOPK;
    #pragma unroll
    for (int i = 3; i >= 0; --i) {         // high bin = larger value
        unsigned sufThis = run + loc[i];
        if (sufThis >= r && run < r) { s_bin = tid * 4 + i; s_r2 = r - run; }
        run = sufThis;
    }
    __syncthreads();
    const unsigned bin = s_bin, r2 = s_r2;

    // collect low-21-bit remainders of prefix-matching elements
    #pragma unroll
    for (int j = 0; j < 4; j++) {
        if ((u[j] >> 21) == bin) {
            unsigned p = atomicAdd(&s_cnt, 1u);
            s_low[p] = u[j] & 0x1FFFFFu;
        }
    }
    __syncthreads();
    const unsigned c = s_cnt;
    for (unsigned p = tid; p < c; p += 256) {
        unsigned x = s_low[p];
        unsigned cg = 0, ce = 0;
        for (unsigned q = 0; q < c; ++q) {
            unsigned yq = s_low[q];
            cg += (yq > x);
            ce += (yq == x);
        }
        if (cg < r2 && cg + ce >= r2) s_T = (bin << 21) | x;
    }
    __syncthreads();
    const unsigned T = s_T;   // exact bit pattern of 50th-largest |v|

    // epilogue: soft-threshold + exact top-k passthrough
    float thv = theta[it];
    ushort4 nh4, nl4;
    unsigned short* nhp = reinterpret_cast<unsigned short*>(&nh4);
    unsigned short* nlp = reinterpret_cast<unsigned short*>(&nl4);
    float ov[4];
    #pragma unroll
    for (int j = 0; j < 4; j++) {
        float th = thv / (10.0f * fabsf(xo[j]) + 1.0f);   // theta * g(|x|), EPS=0.1
        float a = fabsf(v[j]);
        float st = copysignf(fmaxf(a - th, 0.0f), v[j]);
        float outv = (u[j] > T) ? v[j] : st;
        if (!LAST) {
            unsigned short h = f2bf(outv);
            nhp[j] = h;
            nlp[j] = f2bf(outv - bf2f(h));
        }
        ov[j] = outv;
    }
    if (!LAST) {
        *reinterpret_cast<ushort4*>(&Xh[base]) = nh4;
        *reinterpret_cast<ushort4*>(&Xl[base]) = nl4;
    }
    if (LAST)
        *reinterpret_cast<float4*>(&out[base]) = *reinterpret_cast<float4*>(ov);
}

__global__ void tail_kernel(float* __restrict__ out) {
    if (threadIdx.x < 32) out[(size_t)NB * NN + threadIdx.x] = 0.0f;
}

extern "C" void kernel_launch(void* const* d_in, const int* in_sizes, int n_in,
                              void* d_out, int out_size, void* d_ws, size_t ws_size,
                              hipStream_t stream) {
    const float* y     = (const float*)d_in[0];
    const float* phi   = (const float*)d_in[1];
    const float* W     = (const float*)d_in[2];
    const float* gamma = (const float*)d_in[3];
    const float* theta = (const float*)d_in[4];
    float* out = (float*)d_out;

    char* ws = (char*)d_ws;
    size_t off = 0;
    unsigned short* Xh  = (unsigned short*)(ws + off); off += (size_t)NB * NN * 2;  // 32MB
    unsigned short* Xl  = (unsigned short*)(ws + off); off += (size_t)NB * NN * 2;  // 32MB
    unsigned short* Rth = (unsigned short*)(ws + off); off += (size_t)NB * NM * 2;  // 8MB
    unsigned short* Rtl = (unsigned short*)(ws + off); off += (size_t)NB * NM * 2;  // 8MB
    unsigned short* Ph  = (unsigned short*)(ws + off); off += (size_t)NM * NN * 2;  // 512KB
    unsigned short* Pl  = (unsigned short*)(ws + off); off += (size_t)NM * NN * 2;
    unsigned short* Wth = (unsigned short*)(ws + off); off += (size_t)NN * NM * 2;
    unsigned short* Wtl = (unsigned short*)(ws + off); off += (size_t)NN * NM * 2;
    float* C = out;   // C scratch aliases output (read-before-write per thread)

    split_phi_kernel<<<(NM * NN) / 256, 256, 0, stream>>>(phi, Ph, Pl);
    transpose_split_W<<<dim3(NN / 32, NM / 32), dim3(32, 8), 0, stream>>>(W, Wth, Wtl);

    // it = 0: X == 0 -> Rt = -y directly; no memsets, no gemm1 on zeros
    rt_init_kernel<<<(NB * NM) / (256 * 4), 256, 0, stream>>>(y, Rth, Rtl);
    gemm2_mfma<<<dim3(NB / BM2, NN / BN2), 256, 0, stream>>>(Rth, Rtl, Wth, Wtl, C);
    update_kernel<1, 0><<<NB, 256, 0, stream>>>(C, Xh, Xl, gamma, theta, 0, out);

    for (int it = 1; it < NITER - 1; ++it) {
        gemm1_mfma<<<dim3(NB / BM1, NM / BN1), 256, 0, stream>>>(Xh, Xl, Ph, Pl, y, Rth, Rtl);
        gemm2_mfma<<<dim3(NB / BM2, NN / BN2), 256, 0, stream>>>(Rth, Rtl, Wth, Wtl, C);
        update_kernel<0, 0><<<NB, 256, 0, stream>>>(C, Xh, Xl, gamma, theta, it, out);
    }
    // it = 15: X write is dead; only `out` is produced
    gemm1_mfma<<<dim3(NB / BM1, NM / BN1), 256, 0, stream>>>(Xh, Xl, Ph, Pl, y, Rth, Rtl);
    gemm2_mfma<<<dim3(NB / BM2, NN / BN2), 256, 0, stream>>>(Rth, Rtl, Wth, Wtl, C);
    update_kernel<0, 1><<<NB, 256, 0, stream>>>(C, Xh, Xl, gamma, theta, NITER - 1, out);

    tail_kernel<<<1, 32, 0, stream>>>(out);
}

// Round 12
// 1909.296 us; speedup vs baseline: 1.0203x; 1.0203x over previous
//
#include <hip/hip_runtime.h>
#include <cstdint>

#define NB 16384   // batch
#define NM 256     // M
#define NN 1024    // N
#define NITER 16
#define TOPK 50

typedef __attribute__((ext_vector_type(8))) short short8;   // 8 bf16 = 4 VGPRs
typedef __attribute__((ext_vector_type(4))) float f32x4;

__device__ inline unsigned short f2bf(float x) {            // RNE fp32 -> bf16
    unsigned u = __float_as_uint(x);
    return (unsigned short)((u + 0x7FFFu + ((u >> 16) & 1u)) >> 16);
}
__device__ inline float bf2f(unsigned short h) {
    return __uint_as_float(((unsigned)h) << 16);
}
__device__ inline void gload16(const void* g, void* lds) {  // 16B global -> LDS
    __builtin_amdgcn_global_load_lds(
        (const __attribute__((address_space(1))) unsigned*)g,
        (__attribute__((address_space(3))) unsigned*)lds, 16, 0, 0);
}

// ------------- precompute: element-wise split of phi (NM x NN) -------------
__global__ __launch_bounds__(256) void split_phi_kernel(const float* __restrict__ phi,
                                                        unsigned short* __restrict__ h,
                                                        unsigned short* __restrict__ l) {
    int i = blockIdx.x * 256 + threadIdx.x;
    float v = phi[i];
    unsigned short hh = f2bf(v);
    h[i] = hh;
    l[i] = f2bf(v - bf2f(hh));
}

// -------- precompute: W (NM x NN) -> Wt (NN x NM) transposed + split -------
__global__ __launch_bounds__(256) void transpose_split_W(const float* __restrict__ W,
                                                         unsigned short* __restrict__ th,
                                                         unsigned short* __restrict__ tl) {
    __shared__ float tile[32][33];
    int n0 = blockIdx.x * 32;
    int m0 = blockIdx.y * 32;
    int tx = threadIdx.x;   // 0..31
    int ty = threadIdx.y;   // 0..7
    #pragma unroll
    for (int i = 0; i < 32; i += 8)
        tile[ty + i][tx] = W[(size_t)(m0 + ty + i) * NN + n0 + tx];
    __syncthreads();
    #pragma unroll
    for (int i = 0; i < 32; i += 8) {
        float v = tile[tx][ty + i];
        unsigned short hh = f2bf(v);
        size_t idx = (size_t)(n0 + ty + i) * NM + m0 + tx;
        th[idx] = hh;
        tl[idx] = f2bf(v - bf2f(hh));
    }
}

// ---- it=0 shortcut: X==0 -> Rt = -y (split). Replaces memsets + gemm1. ----
__global__ __launch_bounds__(256) void rt_init_kernel(const float* __restrict__ y,
                                                      unsigned short* __restrict__ Rth,
                                                      unsigned short* __restrict__ Rtl) {
    size_t i = ((size_t)blockIdx.x * 256 + threadIdx.x) * 4;
    float4 v4 = *reinterpret_cast<const float4*>(&y[i]);
    float vv[4] = {v4.x, v4.y, v4.z, v4.w};
    ushort4 h4, l4;
    unsigned short* hp = reinterpret_cast<unsigned short*>(&h4);
    unsigned short* lp = reinterpret_cast<unsigned short*>(&l4);
    #pragma unroll
    for (int e = 0; e < 4; ++e) {
        float v = -vv[e];
        unsigned short h = f2bf(v);
        hp[e] = h;
        lp[e] = f2bf(v - bf2f(h));
    }
    *reinterpret_cast<ushort4*>(&Rth[i]) = h4;
    *reinterpret_cast<ushort4*>(&Rtl[i]) = l4;
}

// ---- GEMM1: Rt(B x NM) = X(B x NN) @ phiT - y ----
// 64x64 tile: 1024 blocks, 4 blocks/CU (16 waves/CU), LDS 16 KB.
#define BM1 64
#define BN1 64
#define BK  32
__global__ __launch_bounds__(256) void gemm1_mfma(const unsigned short* __restrict__ Xh,
                                                  const unsigned short* __restrict__ Xl,
                                                  const unsigned short* __restrict__ Ph,
                                                  const unsigned short* __restrict__ Pl,
                                                  const float* __restrict__ y,
                                                  unsigned short* __restrict__ Rth,
                                                  unsigned short* __restrict__ Rtl) {
    __shared__ unsigned short sAh[BM1 * BK];  // 4KB each, row = 32 elem = 64B
    __shared__ unsigned short sAl[BM1 * BK];
    __shared__ unsigned short sBh[BN1 * BK];
    __shared__ unsigned short sBl[BN1 * BK];

    const int tid = threadIdx.x, wave = tid >> 6, lane = tid & 63;
    const int b0 = blockIdx.x * BM1, n0 = blockIdx.y * BN1;
    const int wm = (wave & 1) * 32, wn = (wave >> 1) * 32;
    const int row16 = lane & 15, quad = lane >> 4;

    f32x4 acc[2][2];
    #pragma unroll
    for (int i = 0; i < 2; i++)
        #pragma unroll
        for (int j = 0; j < 2; j++) acc[i][j] = (f32x4){0.f, 0.f, 0.f, 0.f};

    for (int k0 = 0; k0 < NN; k0 += BK) {
        {   // stage A+B: one 16B chunk per thread per array (4KB tiles)
            int o = tid * 16;                  // byte offset in tile
            int row = o >> 6, colb = o & 63;
            size_t gA = (size_t)(b0 + row) * NN + k0 + (colb >> 1);
            gload16(&Xh[gA], (char*)sAh + o);
            gload16(&Xl[gA], (char*)sAl + o);
            size_t gB = (size_t)(n0 + row) * NN + k0 + (colb >> 1);
            gload16(&Ph[gB], (char*)sBh + o);
            gload16(&Pl[gB], (char*)sBl + o);
        }
        __syncthreads();
        short8 a[2], bh[2], bl[2];
        #pragma unroll
        for (int j = 0; j < 2; ++j) {
            int off = (wn + j * 16 + row16) * 64 + quad * 16;
            bh[j] = *(const short8*)((const char*)sBh + off);
            bl[j] = *(const short8*)((const char*)sBl + off);
        }
        #pragma unroll
        for (int i = 0; i < 2; ++i)
            a[i] = *(const short8*)((const char*)sAh + (wm + i * 16 + row16) * 64 + quad * 16);
        #pragma unroll
        for (int i = 0; i < 2; ++i)
            #pragma unroll
            for (int j = 0; j < 2; ++j) {
                acc[i][j] = __builtin_amdgcn_mfma_f32_16x16x32_bf16(a[i], bh[j], acc[i][j], 0, 0, 0);
                acc[i][j] = __builtin_amdgcn_mfma_f32_16x16x32_bf16(a[i], bl[j], acc[i][j], 0, 0, 0);
            }
        #pragma unroll
        for (int i = 0; i < 2; ++i)
            a[i] = *(const short8*)((const char*)sAl + (wm + i * 16 + row16) * 64 + quad * 16);
        #pragma unroll
        for (int i = 0; i < 2; ++i)
            #pragma unroll
            for (int j = 0; j < 2; ++j)
                acc[i][j] = __builtin_amdgcn_mfma_f32_16x16x32_bf16(a[i], bh[j], acc[i][j], 0, 0, 0);
        __syncthreads();
    }
    #pragma unroll
    for (int i = 0; i < 2; ++i)
        #pragma unroll
        for (int j = 0; j < 2; ++j)
            #pragma unroll
            for (int r = 0; r < 4; ++r) {
                int gm = b0 + wm + i * 16 + quad * 4 + r;
                int gn = n0 + wn + j * 16 + row16;
                size_t idx = (size_t)gm * NM + gn;
                float v = acc[i][j][r] - y[idx];
                unsigned short h = f2bf(v);
                Rth[idx] = h;
                Rtl[idx] = f2bf(v - bf2f(h));
            }
}

// ---- GEMM2 lean: C(B x NN) = Rt(B x NM) @ W(NM x NN), raw f32 out ----
#define BM2 128
#define BN2 128
__global__ __launch_bounds__(256) void gemm2_mfma(const unsigned short* __restrict__ Rth,
                                                  const unsigned short* __restrict__ Rtl,
                                                  const unsigned short* __restrict__ Wth,
                                                  const unsigned short* __restrict__ Wtl,
                                                  float* __restrict__ C) {
    __shared__ unsigned short sAh[BM2 * BK];  // 8KB each
    __shared__ unsigned short sAl[BM2 * BK];
    __shared__ unsigned short sBh[BN2 * BK];
    __shared__ unsigned short sBl[BN2 * BK];

    const int tid = threadIdx.x, wave = tid >> 6, lane = tid & 63;
    const int b0 = blockIdx.x * BM2, n0 = blockIdx.y * BN2;
    const int wm = (wave & 1) * 64, wn = (wave >> 1) * 64;
    const int row16 = lane & 15, quad = lane >> 4;

    f32x4 acc[4][4];
    #pragma unroll
    for (int i = 0; i < 4; i++)
        #pragma unroll
        for (int j = 0; j < 4; j++) acc[i][j] = (f32x4){0.f, 0.f, 0.f, 0.f};

    for (int k0 = 0; k0 < NM; k0 += BK) {
        #pragma unroll
        for (int c = 0; c < 2; ++c) {
            int o = (wave * 2 + c) * 1024 + lane * 16;
            int row = o >> 6, colb = o & 63;
            size_t gA = (size_t)(b0 + row) * NM + k0 + (colb >> 1);
            gload16(&Rth[gA], (char*)sAh + o);
            gload16(&Rtl[gA], (char*)sAl + o);
            size_t gB = (size_t)(n0 + row) * NM + k0 + (colb >> 1);
            gload16(&Wth[gB], (char*)sBh + o);
            gload16(&Wtl[gB], (char*)sBl + o);
        }
        __syncthreads();
        short8 a[4], bh[4], bl[4];
        #pragma unroll
        for (int j = 0; j < 4; ++j) {
            int off = (wn + j * 16 + row16) * 64 + quad * 16;
            bh[j] = *(const short8*)((const char*)sBh + off);
            bl[j] = *(const short8*)((const char*)sBl + off);
        }
        #pragma unroll
        for (int i = 0; i < 4; ++i)
            a[i] = *(const short8*)((const char*)sAh + (wm + i * 16 + row16) * 64 + quad * 16);
        #pragma unroll
        for (int i = 0; i < 4; ++i)
            #pragma unroll
            for (int j = 0; j < 4; ++j) {
                acc[i][j] = __builtin_amdgcn_mfma_f32_16x16x32_bf16(a[i], bh[j], acc[i][j], 0, 0, 0);
                acc[i][j] = __builtin_amdgcn_mfma_f32_16x16x32_bf16(a[i], bl[j], acc[i][j], 0, 0, 0);
            }
        #pragma unroll
        for (int i = 0; i < 4; ++i)
            a[i] = *(const short8*)((const char*)sAl + (wm + i * 16 + row16) * 64 + quad * 16);
        #pragma unroll
        for (int i = 0; i < 4; ++i)
            #pragma unroll
            for (int j = 0; j < 4; ++j)
                acc[i][j] = __builtin_amdgcn_mfma_f32_16x16x32_bf16(a[i], bh[j], acc[i][j], 0, 0, 0);
        __syncthreads();
    }
    #pragma unroll
    for (int i = 0; i < 4; ++i)
        #pragma unroll
        for (int j = 0; j < 4; ++j)
            #pragma unroll
            for (int r = 0; r < 4; ++r) {
                int gmr = b0 + wm + i * 16 + quad * 4 + r;
                int gn = n0 + wn + j * 16 + row16;
                C[(size_t)gmr * NN + gn] = acc[i][j][r];
            }
}

// -------- update: v = x - gamma*c, exact top-50 |v| via 1024-bin select ----
// LAST: final iteration's X write is dead (only `out` is consumed) -> skip.
template <int FIRST, int LAST>
__global__ __launch_bounds__(256) void update_kernel(const float* __restrict__ C,
                                                     unsigned short* __restrict__ Xh,
                                                     unsigned short* __restrict__ Xl,
                                                     const float* __restrict__ gamma,
                                                     const float* __restrict__ theta,
                                                     int it,
                                                     float* __restrict__ out) {
    __shared__ unsigned hist[1024];    // 4KB
    __shared__ unsigned wtot[4];
    __shared__ unsigned s_bin;
    __shared__ unsigned s_r2;
    __shared__ unsigned s_cnt;
    __shared__ unsigned s_T;
    __shared__ unsigned s_low[1024];   // 4KB worst case

    const int b = blockIdx.x, tid = threadIdx.x;
    const int lane = tid & 63, wave = tid >> 6;
    const size_t base = (size_t)b * NN + tid * 4;
    const float gm = gamma[it];

    float4 cc = *reinterpret_cast<const float4*>(&C[base]);
    float c4[4] = {cc.x, cc.y, cc.z, cc.w};

    ushort4 xh4, xl4;
    float xo[4];
    if (FIRST) {
        xo[0] = xo[1] = xo[2] = xo[3] = 0.0f;
    } else {
        xh4 = *reinterpret_cast<const ushort4*>(&Xh[base]);
        xl4 = *reinterpret_cast<const ushort4*>(&Xl[base]);
        const unsigned short* xhp = reinterpret_cast<const unsigned short*>(&xh4);
        const unsigned short* xlp = reinterpret_cast<const unsigned short*>(&xl4);
        #pragma unroll
        for (int j = 0; j < 4; j++) xo[j] = bf2f(xhp[j]) + bf2f(xlp[j]);
    }

    float v[4];
    unsigned u[4];
    #pragma unroll
    for (int j = 0; j < 4; j++) {
        v[j] = xo[j] - gm * c4[j];
        u[j] = __float_as_uint(fabsf(v[j]));
    }

    // clear
    uint4 z4 = {0u, 0u, 0u, 0u};
    reinterpret_cast<uint4*>(hist)[tid] = z4;
    if (tid == 0) s_cnt = 0;
    __syncthreads();

    #pragma unroll
    for (int j = 0; j < 4; j++) atomicAdd(&hist[u[j] >> 21], 1u);
    __syncthreads();

    // thread t owns bins [t*4, t*4+4)
    unsigned loc[4];
    uint4 h0 = reinterpret_cast<const uint4*>(hist)[tid];
    loc[0] = h0.x; loc[1] = h0.y; loc[2] = h0.z; loc[3] = h0.w;
    unsigned lsum = loc[0] + loc[1] + loc[2] + loc[3];

    // wave-level inclusive suffix scan of lsum (no LDS, no barriers)
    unsigned s = lsum;
    #pragma unroll
    for (int off = 1; off < 64; off <<= 1) {
        unsigned o = __shfl_down(s, off, 64);
        if (lane + off < 64) s += o;
    }
    if (lane == 0) wtot[wave] = s;   // wave total
    __syncthreads();
    unsigned after_wave = 0;
    #pragma unroll
    for (int w = 0; w < 4; ++w)
        if (w > wave) after_wave += wtot[w];
    unsigned S_incl = s + after_wave;      // suffix incl. this thread's bins
    unsigned run = S_incl - lsum;          // suffix of all higher bins

    const unsigned r = TOPK;
    #pragma unroll
    for (int i = 3; i >= 0; --i) {         // high bin = larger value
        unsigned sufThis = run + loc[i];
        if (sufThis >= r && run < r) { s_bin = tid * 4 + i; s_r2 = r - run; }
        run = sufThis;
    }
    __syncthreads();
    const unsigned bin = s_bin, r2 = s_r2;

    // collect low-21-bit remainders of prefix-matching elements
    #pragma unroll
    for (int j = 0; j < 4; j++) {
        if ((u[j] >> 21) == bin) {
            unsigned p = atomicAdd(&s_cnt, 1u);
            s_low[p] = u[j] & 0x1FFFFFu;
        }
    }
    __syncthreads();
    const unsigned c = s_cnt;
    for (unsigned p = tid; p < c; p += 256) {
        unsigned x = s_low[p];
        unsigned cg = 0, ce = 0;
        for (unsigned q = 0; q < c; ++q) {
            unsigned yq = s_low[q];
            cg += (yq > x);
            ce += (yq == x);
        }
        if (cg < r2 && cg + ce >= r2) s_T = (bin << 21) | x;
    }
    __syncthreads();
    const unsigned T = s_T;   // exact bit pattern of 50th-largest |v|

    // epilogue: soft-threshold + exact top-k passthrough.
    // th scales only the soft branch (never T, never passthrough v) -> HW rcp
    // (~1e-6 rel) is safe; saves 4 full-rate divides of VALU per thread.
    float thv = theta[it];
    ushort4 nh4, nl4;
    unsigned short* nhp = reinterpret_cast<unsigned short*>(&nh4);
    unsigned short* nlp = reinterpret_cast<unsigned short*>(&nl4);
    float ov[4];
    #pragma unroll
    for (int j = 0; j < 4; j++) {
        float th = thv * __builtin_amdgcn_rcpf(10.0f * fabsf(xo[j]) + 1.0f);
        float a = fabsf(v[j]);
        float st = copysignf(fmaxf(a - th, 0.0f), v[j]);
        float outv = (u[j] > T) ? v[j] : st;
        if (!LAST) {
            unsigned short h = f2bf(outv);
            nhp[j] = h;
            nlp[j] = f2bf(outv - bf2f(h));
        }
        ov[j] = outv;
    }
    if (!LAST) {
        *reinterpret_cast<ushort4*>(&Xh[base]) = nh4;
        *reinterpret_cast<ushort4*>(&Xl[base]) = nl4;
    }
    if (LAST)
        *reinterpret_cast<float4*>(&out[base]) = *reinterpret_cast<float4*>(ov);
}

__global__ void tail_kernel(float* __restrict__ out) {
    if (threadIdx.x < 32) out[(size_t)NB * NN + threadIdx.x] = 0.0f;
}

extern "C" void kernel_launch(void* const* d_in, const int* in_sizes, int n_in,
                              void* d_out, int out_size, void* d_ws, size_t ws_size,
                              hipStream_t stream) {
    const float* y     = (const float*)d_in[0];
    const float* phi   = (const float*)d_in[1];
    const float* W     = (const float*)d_in[2];
    const float* gamma = (const float*)d_in[3];
    const float* theta = (const float*)d_in[4];
    float* out = (float*)d_out;

    char* ws = (char*)d_ws;
    size_t off = 0;
    unsigned short* Xh  = (unsigned short*)(ws + off); off += (size_t)NB * NN * 2;  // 32MB
    unsigned short* Xl  = (unsigned short*)(ws + off); off += (size_t)NB * NN * 2;  // 32MB
    unsigned short* Rth = (unsigned short*)(ws + off); off += (size_t)NB * NM * 2;  // 8MB
    unsigned short* Rtl = (unsigned short*)(ws + off); off += (size_t)NB * NM * 2;  // 8MB
    unsigned short* Ph  = (unsigned short*)(ws + off); off += (size_t)NM * NN * 2;  // 512KB
    unsigned short* Pl  = (unsigned short*)(ws + off); off += (size_t)NM * NN * 2;
    unsigned short* Wth = (unsigned short*)(ws + off); off += (size_t)NN * NM * 2;
    unsigned short* Wtl = (unsigned short*)(ws + off); off += (size_t)NN * NM * 2;
    float* C = out;   // C scratch aliases output (read-before-write per thread)

    split_phi_kernel<<<(NM * NN) / 256, 256, 0, stream>>>(phi, Ph, Pl);
    transpose_split_W<<<dim3(NN / 32, NM / 32), dim3(32, 8), 0, stream>>>(W, Wth, Wtl);

    // it = 0: X == 0 -> Rt = -y directly; no memsets, no gemm1 on zeros
    rt_init_kernel<<<(NB * NM) / (256 * 4), 256, 0, stream>>>(y, Rth, Rtl);
    gemm2_mfma<<<dim3(NB / BM2, NN / BN2), 256, 0, stream>>>(Rth, Rtl, Wth, Wtl, C);
    update_kernel<1, 0><<<NB, 256, 0, stream>>>(C, Xh, Xl, gamma, theta, 0, out);

    for (int it = 1; it < NITER - 1; ++it) {
        gemm1_mfma<<<dim3(NB / BM1, NM / BN1), 256, 0, stream>>>(Xh, Xl, Ph, Pl, y, Rth, Rtl);
        gemm2_mfma<<<dim3(NB / BM2, NN / BN2), 256, 0, stream>>>(Rth, Rtl, Wth, Wtl, C);
        update_kernel<0, 0><<<NB, 256, 0, stream>>>(C, Xh, Xl, gamma, theta, it, out);
    }
    // it = 15: X write is dead; only `out` is produced
    gemm1_mfma<<<dim3(NB / BM1, NM / BN1), 256, 0, stream>>>(Xh, Xl, Ph, Pl, y, Rth, Rtl);
    gemm2_mfma<<<dim3(NB / BM2, NN / BN2), 256, 0, stream>>>(Rth, Rtl, Wth, Wtl, C);
    update_kernel<0, 1><<<NB, 256, 0, stream>>>(C, Xh, Xl, gamma, theta, NITER - 1, out);

    tail_kernel<<<1, 32, 0, stream>>>(out);
}